// Round 7
// baseline (484.447 us; speedup 1.0000x reference)
//
#include <hip/hip_runtime.h>
#include <math.h>

// SNN forward, fused. Inputs f32, output f32 [2048][200].
// R25 = R24 (scratch-free, 250us/dispatch) + issue-count cuts:
//  - spike capture via v_writelane_b32 inline asm (builtin missing on this
//    toolchain, the INSTRUCTION exists): 2 VALU/step vs cmp_eq+2x cndmask_b64.
//  - ubits XOR swizzle restored (R24 exonerated it; scratch arrays were the
//    R21-23 regressor): physical dword = logical ^ (row&12). Bijective,
//    preserves b64/b128 alignment (XOR touches bits 2-3 only), bitmask b128
//    reads 4-way -> 2-way (free).
//  - output layer: wave-uniform skip of all-zero-weight col fragments
//    (wave 3, i>=1 covers cols 208..255 > NOUT): -24 MFMA/tile on wave 3.
//  - everything else identical to R24: 160x8dw ubits (no zero-init, rows
//    150-159 zeroed by scan guard), lambda-instantiated fp8 layers (no
//    runtime-indexed stack arrays), layer-1 A direct from global x,
//    LDS 32768 B, launch_bounds (256,4) (no VGPR cap).

#define T_N 150
#define DIN 20
#define H 256
#define NOUT 200
#define NMT 10
#define CST 20             // sc col stride (f32): 16 rows + 4 pad

// d_ws layout: [0,5120) shorts = bf16 W1; then fp8 bytes W2,W3,W4,Wo
#define N_W1 5120
#define F8_W2 0
#define F8_W3 65536
#define F8_W4 131072
#define F8_WO 196608
#define F8_TOT 247808

typedef short s16x8 __attribute__((ext_vector_type(8)));
typedef float f32x4 __attribute__((ext_vector_type(4)));
typedef unsigned int u32x4 __attribute__((ext_vector_type(4)));

__device__ __forceinline__ unsigned short f2bf(float f) {
  union { float f; unsigned int i; } v; v.f = f;
  unsigned int r = v.i + 0x7FFFu + ((v.i >> 16) & 1u);
  return (unsigned short)(r >> 16);
}

// f32 -> OCP e4m3 (RNE, handles subnormals; inputs |f| <= 0.25, no sat needed)
__device__ __forceinline__ unsigned char f2e4m3(float f) {
  union { float f; unsigned u; } v; v.f = f;
  unsigned s = (v.u >> 24) & 0x80u;
  unsigned mag = v.u & 0x7FFFFFFFu;
  if (mag == 0) return (unsigned char)s;
  int e = (int)(mag >> 23) - 127;
  unsigned man = mag & 0x7FFFFFu;
  unsigned q;
  if (e >= -6) {
    unsigned r = man + 0x7FFFFu + ((man >> 20) & 1u);
    if (r >= 0x800000u) { e += 1; r -= 0x800000u; }
    q = ((unsigned)(e + 7) << 3) | (r >> 20);
  } else {
    unsigned mant = 0x800000u | man;
    int sh = 14 - e;
    if (sh > 31) q = 0;
    else {
      unsigned fl = mant >> sh;
      unsigned rem = mant & ((1u << sh) - 1u);
      unsigned half = 1u << (sh - 1);
      q = fl + ((rem > half || (rem == half && (fl & 1))) ? 1u : 0u);
    }
  }
  return (unsigned char)(s | q);
}

__global__ void cvt_weights(const float* __restrict__ W1, const float* __restrict__ W2,
                            const float* __restrict__ W3, const float* __restrict__ W4,
                            const float* __restrict__ Wo, unsigned short* __restrict__ ws) {
  int idx = blockIdx.x * blockDim.x + threadIdx.x;
  int stride = gridDim.x * blockDim.x;
  for (int i = idx; i < N_W1; i += stride) ws[i] = f2bf(W1[i]);
  unsigned char* f8 = (unsigned char*)(ws + N_W1);
  for (int i = idx; i < F8_TOT; i += stride) {
    float v;
    if (i < F8_W3)      v = W2[i - F8_W2];
    else if (i < F8_W4) v = W3[i - F8_W3];
    else if (i < F8_WO) v = W4[i - F8_W4];
    else                v = Wo[i - F8_WO];
    f8[i] = f2e4m3(v);
  }
}

// expand 8 spike bits -> 8 fp8 e4m3 bytes (0x00 / 0x38) packed in a long
// (used only to BUILD the LDS LUT).
__device__ __forceinline__ long expand8_f8(unsigned t) {
  unsigned lo = ((t & 0xFu) * 0x204081u) & 0x01010101u;
  unsigned hi = ((t >> 4) * 0x204081u) & 0x01010101u;
  lo *= 0x38u; hi *= 0x38u;
  union { unsigned u[2]; long l; } cv; cv.u[0] = lo; cv.u[1] = hi;
  return cv.l;
}

__global__ __launch_bounds__(256, 4) void snn_fused(
    const float* __restrict__ x,             // [2048][150][20] f32
    const unsigned short* __restrict__ wsb,  // d_ws: bf16 W1 + fp8 W2..Wo
    const float* __restrict__ b1,            // [256] f32
    const float* __restrict__ b2,
    const float* __restrict__ b3,
    const float* __restrict__ b4,
    float* __restrict__ out)                 // [2048][200] f32
{
  __shared__ float sc[5120];               // 20480 B: col-major C scratch
  __shared__ unsigned int ub0[1280];       //  5120 B: spike bits, 160 rows x 8 dw
  __shared__ unsigned int ub1[1280];       //  5120 B
  __shared__ long lut[256];                //  2048 B: byte -> 8 fp8 spikes
                                           // total 32768 B exactly

  const int tid  = threadIdx.x;
  const int lane = tid & 63;
  const int wave = tid >> 6;    // 0..3
  const int c16  = lane & 15;
  const int quad = lane >> 4;
  const int shq  = quad * 8;
  const int shq2 = (quad == 3) ? 16 : shq;  // quad3 re-reads quad2's slice (its weights are 0)
  const int bidx = blockIdx.x;
  const int colw = 64 * wave;   // wave owns cols [64w, 64w+64)
  const int cb   = colw + c16;

  const unsigned char* f8 = (const unsigned char*)(wsb + N_W1);

  auto store_c = [&](f32x4* c) {
    #pragma unroll
    for (int i = 0; i < 4; ++i)
      *(f32x4*)&sc[(cb + 16 * i) * CST + quad * 4] = c[i];
  };

  // fused membrane scan, two-half form; 64 lanes own the wave's 64 cols.
  // Ballot masks captured per-row via v_writelane (2 VALU/step).
  // Rows t>=150 (mt=9, lanes 6..15) store keep=0 -> no zero-init needed.
  auto scan_tile = [&](int mt, float& m, unsigned int* wb) {
    const f32x4* vp = (const f32x4*)&sc[(colw + lane) * CST];
    unsigned int klo = 0, khi = 0;
    #pragma unroll
    for (int h = 0; h < 2; ++h) {
      f32x4 v0 = vp[2 * h], v1 = vp[2 * h + 1];
      #pragma unroll
      for (int rr = 0; rr < 8; ++rr) {
        const int r = 8 * h + rr;
        int t = mt * 16 + r;
        if (t < T_N) {  // block-uniform
          float inp = (rr < 4) ? v0[rr & 3] : v1[rr & 3];
          float sel = (m > 1.0f) ? (inp - 1.0f) : inp;
          m = 0.9f * m + sel;
          unsigned long long msk = __ballot(m > 1.0f);
          asm("v_writelane_b32 %0, %2, %4\n\t"
              "v_writelane_b32 %1, %3, %4"
              : "+v"(klo), "+v"(khi)
              : "s"((unsigned)msk), "s"((unsigned)(msk >> 32)), "i"(r));
        }
      }
    }
    int row = mt * 16 + lane;
    if (lane < 16) {
      union { unsigned int u[2]; unsigned long long l; } cv;
      cv.u[0] = klo; cv.u[1] = khi;
      int dwi = (row * 8 + 2 * wave) ^ (row & 12);   // XOR swizzle, 8B-aligned
      *(unsigned long long*)&wb[dwi] = cv.l;
    }
  };

  lut[tid] = expand8_f8((unsigned)tid);  // visible after post-layer-1 barrier

  // ---- layer 1 (bf16): x @ W1^T (K=20 pad 32) -> ub0; barrier-free ----
  // A-fragments straight from global x (block slice 12 KB, L1/L2-resident).
  {
    s16x8 w1f[4];
    #pragma unroll
    for (int i = 0; i < 4; ++i) {
      int n = cb + 16 * i;
      #pragma unroll
      for (int j = 0; j < 8; ++j) {
        int k = shq + j;
        w1f[i][j] = (k < DIN) ? (short)wsb[n * DIN + k] : (short)0;
      }
      asm volatile("" : "+v"(w1f[i]));
    }
    float bc[4];
    #pragma unroll
    for (int i = 0; i < 4; ++i) bc[i] = b1[cb + 16 * i];
    const float* xrow = x + (size_t)bidx * (T_N * DIN);
    float m = 0.0f;
    for (int mt = 0; mt < NMT; ++mt) {
      int tr = mt * 16 + c16; if (tr > T_N - 1) tr = T_N - 1;  // global-x OOB guard only
      const float* p = xrow + tr * DIN + shq2;   // 16B-aligned (80B rows, shq2 in {0,8,16})
      f32x4 v0 = *(const f32x4*)p;
      f32x4 v1 = {0.f, 0.f, 0.f, 0.f};
      if (shq2 < 16) v1 = *(const f32x4*)(p + 4);  // quads 0,1 only (k<16)
      s16x8 a1;
      #pragma unroll
      for (int j = 0; j < 4; ++j) {
        a1[j]     = (short)f2bf(v0[j]);
        a1[4 + j] = (short)f2bf(v1[j]);   // k=20..23 -> 0 (weights there are 0)
      }
      f32x4 c[4];
      #pragma unroll
      for (int i = 0; i < 4; ++i) { f32x4 z = {bc[i], bc[i], bc[i], bc[i]}; c[i] = z; }
      #pragma unroll
      for (int i = 0; i < 4; ++i)
        c[i] = __builtin_amdgcn_mfma_f32_16x16x32_bf16(a1, w1f[i], c[i], 0, 0, 0);
      if (mt > 0) scan_tile(mt - 1, m, ub0);
      store_c(c);
    }
    scan_tile(9, m, ub0);
  }
  __syncthreads();  // bits0 complete (incl. zero rows 150..159); lut visible

  // ---- layers 2..4 (fp8 weights): barrier-free, bits ping-pong ----
  // Instantiated 3x with constant pointers: NO runtime-indexed stack arrays.
  auto layer_f8 = [&](const unsigned char* wl, const float* __restrict__ bias,
                      const unsigned int* ubr, unsigned int* ubw) {
    __builtin_amdgcn_sched_barrier(0);
    long wf[4][8];
    #pragma unroll
    for (int i = 0; i < 4; ++i) {
      int n = cb + 16 * i;
      #pragma unroll
      for (int ks = 0; ks < 8; ++ks) {
        wf[i][ks] = *(const long*)(wl + n * H + ks * 32 + shq);
        asm volatile("" : "+v"(wf[i][ks]));
      }
    }
    __builtin_amdgcn_sched_barrier(0);
    float bc[4];
    #pragma unroll
    for (int i = 0; i < 4; ++i) bc[i] = bias[cb + 16 * i];
    float m = 0.0f;
    for (int mt = 0; mt < NMT; ++mt) {
      const int trow = mt * 16 + c16;            // 0..159, always in-bounds
      f32x4 c[4];
      #pragma unroll
      for (int i = 0; i < 4; ++i) { f32x4 z = {bc[i], bc[i], bc[i], bc[i]}; c[i] = z; }
      #pragma unroll
      for (int h = 0; h < 2; ++h) {
        u32x4 rm = *(const u32x4*)&ubr[(trow * 8 + 4 * h) ^ (trow & 12)];
        #pragma unroll
        for (int kk = 0; kk < 4; ++kk) {
          long a = lut[(rm[kk] >> shq) & 0xFFu];   // LDS LUT expansion
          int ks = 4 * h + kk;
          #pragma unroll
          for (int i = 0; i < 4; ++i)
            c[i] = __builtin_amdgcn_mfma_f32_16x16x32_fp8_fp8(a, wf[i][ks], c[i], 0, 0, 0);
        }
      }
      if (mt > 0) scan_tile(mt - 1, m, ubw);
      store_c(c);
    }
    scan_tile(9, m, ubw);
    __syncthreads();  // bits[ubw] complete
  };
  layer_f8(f8 + F8_W2, b2, ub0, ub1);
  layer_f8(f8 + F8_W3, b3, ub1, ub0);
  layer_f8(f8 + F8_W4, b4, ub0, ub1);

  // ---- output layer (fp8, reads ub1): GEMM + mo-scan + softmax ----
  {
    __builtin_amdgcn_sched_barrier(0);
    long wo[4][8];
    #pragma unroll
    for (int i = 0; i < 4; ++i) {
      int n = cb + 16 * i;
      bool valid = (n < NOUT);
      #pragma unroll
      for (int ks = 0; ks < 8; ++ks) {
        wo[i][ks] = valid ? *(const long*)(f8 + F8_WO + n * H + ks * 32 + shq) : 0L;
        asm volatile("" : "+v"(wo[i][ks]));
      }
    }
    __builtin_amdgcn_sched_barrier(0);

    float mo = 0.0f;
    float a0 = 0.f, a1 = 0.f, a2 = 0.f, a3 = 0.f;

    auto moscan = [&](int mt) {
      if (tid < 208) {   // wave-local: thread tid scans col tid
        f32x4* vp = (f32x4*)&sc[tid * CST];
        #pragma unroll
        for (int h = 0; h < 2; ++h) {
          f32x4 v0 = vp[2 * h], v1 = vp[2 * h + 1];
          #pragma unroll
          for (int rr = 0; rr < 8; ++rr) {
            int r = 8 * h + rr;
            int t = mt * 16 + r;
            if (t < T_N) {
              float inp = (rr < 4) ? v0[rr & 3] : v1[rr & 3];
              float reset = (mo > 1.0f) ? 1.0f : 0.0f;
              mo = 0.9f * mo + inp - reset;
              if (rr < 4) v0[rr & 3] = mo; else v1[rr & 3] = mo;
            }
          }
          vp[2 * h] = v0; vp[2 * h + 1] = v1;
        }
      }
    };
    auto softmax_t = [&](int mt) {
      #pragma unroll
      for (int rr = 0; rr < 4; ++rr) {
        int r = 4 * wave + rr;
        int t = mt * 16 + r;
        if (t > 50 && t < T_N) {        // wave-uniform
          const float* p = &sc[r];
          float v0 = p[lane * CST];
          float v1 = p[(64 + lane) * CST];
          float v2 = p[(128 + lane) * CST];
          bool has3 = (lane < 8);
          float v3 = has3 ? p[(192 + lane) * CST] : -INFINITY;
          float mx = fmaxf(fmaxf(v0, v1), fmaxf(v2, v3));
          #pragma unroll
          for (int d = 32; d >= 1; d >>= 1) mx = fmaxf(mx, __shfl_xor(mx, d));
          float e0 = __expf(v0 - mx), e1 = __expf(v1 - mx), e2 = __expf(v2 - mx);
          float e3 = has3 ? __expf(v3 - mx) : 0.0f;
          float s = e0 + e1 + e2 + e3;
          #pragma unroll
          for (int d = 32; d >= 1; d >>= 1) s += __shfl_xor(s, d);
          float inv = 1.0f / s;
          a0 += e0 * inv; a1 += e1 * inv; a2 += e2 * inv; a3 += e3 * inv;
        }
      }
    };

    for (int mt = 0; mt < NMT; ++mt) {
      const int trow = mt * 16 + c16;            // 0..159, always in-bounds
      f32x4 c[4];
      #pragma unroll
      for (int i = 0; i < 4; ++i) { f32x4 z = {0.f, 0.f, 0.f, 0.f}; c[i] = z; }
      #pragma unroll
      for (int h = 0; h < 2; ++h) {
        u32x4 rm = *(const u32x4*)&ub1[(trow * 8 + 4 * h) ^ (trow & 12)];
        #pragma unroll
        for (int kk = 0; kk < 4; ++kk) {
          long a = lut[(rm[kk] >> shq) & 0xFFu];   // LDS LUT expansion
          int ks = 4 * h + kk;
          #pragma unroll
          for (int i = 0; i < 4; ++i)
            if (colw + 16 * i < NOUT)             // wave-uniform: wave3 keeps i=0 only
              c[i] = __builtin_amdgcn_mfma_f32_16x16x32_fp8_fp8(a, wo[i][ks], c[i], 0, 0, 0);
        }
      }
      __syncthreads();              // prior softmax done reading sc
      #pragma unroll
      for (int i = 0; i < 4; ++i)
        if (colw + 16 * i < NOUT)                 // skip all-zero fragments
          *(f32x4*)&sc[(cb + 16 * i) * CST + quad * 4] = c[i];
      moscan(mt);                   // wave-local after wave-local store
      __syncthreads();              // membranes visible to all waves
      softmax_t(mt);
    }
    __syncthreads();

    // merge 4 per-wave accumulators via sc, store f32
    sc[wave * 260 + lane]       = a0;
    sc[wave * 260 + 64 + lane]  = a1;
    sc[wave * 260 + 128 + lane] = a2;
    if (lane < 8) sc[wave * 260 + 192 + lane] = a3;
    __syncthreads();
    if (tid < NOUT) {
      float v = sc[tid] + sc[260 + tid] + sc[520 + tid] + sc[780 + tid];
      out[(size_t)bidx * NOUT + tid] = v;
    }
  }
}

extern "C" void kernel_launch(void* const* d_in, const int* in_sizes, int n_in,
                              void* d_out, int out_size, void* d_ws, size_t ws_size,
                              hipStream_t stream) {
  (void)in_sizes; (void)n_in; (void)ws_size; (void)out_size;
  unsigned short* wsb = (unsigned short*)d_ws;
  cvt_weights<<<256, 256, 0, stream>>>(
      (const float*)d_in[1], (const float*)d_in[3], (const float*)d_in[5],
      (const float*)d_in[7], (const float*)d_in[9], wsb);
  snn_fused<<<2048, 256, 0, stream>>>(
      (const float*)d_in[0], wsb,
      (const float*)d_in[2], (const float*)d_in[4],
      (const float*)d_in[6], (const float*)d_in[8],
      (float*)d_out);
}